// Round 1
// baseline (12814.180 us; speedup 1.0000x reference)
//
#include <hip/hip_runtime.h>
#include <stdint.h>

typedef unsigned short u16;
typedef __bf16 bf16x8 __attribute__((ext_vector_type(8)));
typedef float f32x4 __attribute__((ext_vector_type(4)));

#define NLAYER 6
#define DM 768
#define NH 12
#define FD 3072
#define NCLS 10
#define BATCH 8
#define SEQ 1024
#define NTOK (BATCH*SEQ)

__device__ __forceinline__ u16 f2bf(float f) {
  union { float f; unsigned u; } v; v.f = f;
  unsigned u = v.u;
  return (u16)((u + 0x7fffu + ((u >> 16) & 1u)) >> 16);
}

__device__ __forceinline__ void async16(const void* g, void* l) {
  __builtin_amdgcn_global_load_lds(
      (__attribute__((address_space(1))) void*)(void*)g,
      (__attribute__((address_space(3))) void*)l, 16, 0, 0);
}

// ---------------- transpose fp32 [R][C] -> bf16 [C][R], per-layer z ----------------
__global__ __launch_bounds__(256) void transpose_f32_bf16(
    const float* __restrict__ in, u16* __restrict__ out,
    int R, int C, long inLS, long outLS, long outOff)
{
  __shared__ float tile[32][33];
  const float* inp = in + (long)blockIdx.z * inLS;
  u16* outp = out + (long)blockIdx.z * outLS + outOff;
  int c0 = blockIdx.x * 32, r0 = blockIdx.y * 32;
  int tx = threadIdx.x, ty = threadIdx.y;
  #pragma unroll
  for (int j = 0; j < 32; j += 8)
    tile[ty + j][tx] = inp[(long)(r0 + ty + j) * C + c0 + tx];
  __syncthreads();
  #pragma unroll
  for (int j = 0; j < 32; j += 8)
    outp[(long)(c0 + ty + j) * R + r0 + tx] = f2bf(tile[tx][ty + j]);
}

// ---------------- concat q/k/v biases into [NLAYER][2304] ----------------
__global__ void concat_bias(const float* __restrict__ bq, const float* __restrict__ bk,
                            const float* __restrict__ bv, float* __restrict__ qkvb)
{
  int i = blockIdx.x * 256 + threadIdx.x;
  if (i >= NLAYER * 2304) return;
  int layer = i / 2304, c = i % 2304;
  float v;
  if (c < 768) v = bq[layer * 768 + c];
  else if (c < 1536) v = bk[layer * 768 + c - 768];
  else v = bv[layer * 768 + c - 1536];
  qkvb[i] = v;
}

// ---------------- embedding + sinusoidal PE -> x fp32 + x bf16 ----------------
__global__ __launch_bounds__(256) void embed_kernel(
    const int* __restrict__ ids, const float* __restrict__ emb,
    float* __restrict__ x, u16* __restrict__ xb)
{
  int e = (blockIdx.x * 256 + threadIdx.x) * 4;   // flat element, multiple of 4
  int d = e % DM;
  int tok = e / DM;
  int l = tok % SEQ;
  int id = ids[tok];
  float4 em = *(const float4*)(emb + (long)id * DM + d);
  const float cexp = -9.210340371976184f / 768.f;   // -ln(10000)/D
  float div0 = __expf((float)d * cexp);
  float div1 = __expf((float)(d + 2) * cexp);
  float a0 = (float)l * div0, a1 = (float)l * div1;
  em.x += sinf(a0); em.y += cosf(a0);
  em.z += sinf(a1); em.w += cosf(a1);
  *(float4*)(x + e) = em;
  uint2 pk;
  pk.x = f2bf(em.x) | ((unsigned)f2bf(em.y) << 16);
  pk.y = f2bf(em.z) | ((unsigned)f2bf(em.w) << 16);
  *(uint2*)(xb + e) = pk;
}

// ---------------- bf16 MFMA GEMM: C[M][N] = A[M][K] @ BT[N][K]^T + bias ----------------
// m97 structure: 128x128 block tile, BK=32, 4 waves (2x2), global_load_lds x16B staging.
__global__ __launch_bounds__(256) void gemm_bt(
    const u16* __restrict__ A, const u16* __restrict__ BT,
    const float* __restrict__ bias,
    float* __restrict__ Cf, u16* __restrict__ Cb,
    int N, int K, int relu)
{
  __shared__ u16 As[128 * 32];
  __shared__ u16 Bs[128 * 32];
  int tid = threadIdx.x;
  int wave = tid >> 6, lane = tid & 63;
  int wm = (wave >> 1) * 64, wn = (wave & 1) * 64;
  int row16 = lane & 15, quad = lane >> 4;
  long mBase = (long)blockIdx.x * 128;
  long nBase = (long)blockIdx.y * 128;
  int arow = lane >> 2;           // row within 16-row chunk
  int acol = (lane & 3) * 8;      // bf16 col offset

  f32x4 acc[4][4] = {};

  for (int k0 = 0; k0 < K; k0 += 32) {
    __syncthreads();
    int c0 = wave * 2;
    async16(A  + (mBase + c0 * 16      + arow) * (long)K + k0 + acol, As + c0 * 512);
    async16(A  + (mBase + c0 * 16 + 16 + arow) * (long)K + k0 + acol, As + (c0 + 1) * 512);
    async16(BT + (nBase + c0 * 16      + arow) * (long)K + k0 + acol, Bs + c0 * 512);
    async16(BT + (nBase + c0 * 16 + 16 + arow) * (long)K + k0 + acol, Bs + (c0 + 1) * 512);
    __syncthreads();

    bf16x8 aF[4], bF[4];
    #pragma unroll
    for (int i = 0; i < 4; i++)
      aF[i] = *(const bf16x8*)(As + (wm + i * 16 + row16) * 32 + quad * 8);
    #pragma unroll
    for (int j = 0; j < 4; j++)
      bF[j] = *(const bf16x8*)(Bs + (wn + j * 16 + row16) * 32 + quad * 8);
    #pragma unroll
    for (int i = 0; i < 4; i++)
      #pragma unroll
      for (int j = 0; j < 4; j++)
        acc[i][j] = __builtin_amdgcn_mfma_f32_16x16x32_bf16(aF[i], bF[j], acc[i][j], 0, 0, 0);
  }

  #pragma unroll
  for (int j = 0; j < 4; j++) {
    long gn = nBase + wn + j * 16 + row16;
    float bv = bias[gn];
    #pragma unroll
    for (int i = 0; i < 4; i++) {
      #pragma unroll
      for (int r = 0; r < 4; r++) {
        long gm = mBase + wm + i * 16 + quad * 4 + r;
        float v = acc[i][j][r] + bv;
        if (relu) v = fmaxf(v, 0.f);
        long idx = gm * (long)N + gn;
        if (Cf) Cf[idx] = v;
        if (Cb) Cb[idx] = f2bf(v);
      }
    }
  }
}

// ---------------- flash-style attention (VALU), 1 wave = 64 query rows ----------------
// qkv: [NTOK][2304] fp32 (q|k|v each 768 = 12 heads * 64). out: ctx bf16 [NTOK][768]
__global__ __launch_bounds__(64) void attention_kernel(
    const float* __restrict__ qkv, const int* __restrict__ mask,
    u16* __restrict__ ctxb)
{
  __shared__ float Ks[64 * 64];
  __shared__ float Vs[64 * 64];
  __shared__ float negs[64];
  int t = threadIdx.x;
  int qt = blockIdx.x & 15;
  int bh = blockIdx.x >> 4;
  int b = bh / NH, h = bh % NH;
  long rowQ = (long)b * SEQ + qt * 64 + t;
  const float* qp = qkv + rowQ * 2304 + h * 64;
  float q[64], o[64];
  #pragma unroll
  for (int j = 0; j < 16; j++) {
    float4 f = *(const float4*)(qp + j * 4);
    q[j*4+0] = f.x; q[j*4+1] = f.y; q[j*4+2] = f.z; q[j*4+3] = f.w;
  }
  #pragma unroll
  for (int d = 0; d < 64; d++) o[d] = 0.f;
  float mx = -3.0e38f, lsum = 0.f;

  for (int kt = 0; kt < 16; kt++) {
    __syncthreads();
    long kbase = (long)b * SEQ + kt * 64;
    const float* kp = qkv + kbase * 2304 + 768 + h * 64;
    const float* vp = kp + 768;
    #pragma unroll
    for (int it = 0; it < 16; it++) {
      int e = it * 256 + t * 4;
      int r = e >> 6, c = e & 63;
      *(float4*)&Ks[e] = *(const float4*)(kp + (long)r * 2304 + c);
      *(float4*)&Vs[e] = *(const float4*)(vp + (long)r * 2304 + c);
    }
    negs[t] = (mask[kbase + t] == 0) ? -1e9f : 0.f;
    __syncthreads();

    for (int m = 0; m < 64; m++) {
      const float* kr = &Ks[m * 64];
      float s = 0.f;
      #pragma unroll
      for (int j = 0; j < 16; j++) {
        float4 kk = *(const float4*)(kr + j * 4);
        s += q[j*4+0]*kk.x + q[j*4+1]*kk.y + q[j*4+2]*kk.z + q[j*4+3]*kk.w;
      }
      s = s * 0.125f + negs[m];
      if (s > mx) {                       // rare after warmup
        float corr = __expf(mx - s);
        lsum *= corr;
        #pragma unroll
        for (int d = 0; d < 64; d++) o[d] *= corr;
        mx = s;
      }
      float p = __expf(s - mx);
      lsum += p;
      const float* vr = &Vs[m * 64];
      #pragma unroll
      for (int j = 0; j < 16; j++) {
        float4 vv = *(const float4*)(vr + j * 4);
        o[j*4+0] += p*vv.x; o[j*4+1] += p*vv.y; o[j*4+2] += p*vv.z; o[j*4+3] += p*vv.w;
      }
    }
  }
  float inv = 1.f / lsum;
  u16* op = ctxb + rowQ * DM + h * 64;
  #pragma unroll
  for (int j = 0; j < 16; j++) {
    uint2 pk;
    pk.x = f2bf(o[j*4+0]*inv) | ((unsigned)f2bf(o[j*4+1]*inv) << 16);
    pk.y = f2bf(o[j*4+2]*inv) | ((unsigned)f2bf(o[j*4+3]*inv) << 16);
    *(uint2*)(op + j * 4) = pk;
  }
}

// ---------------- fused residual + layernorm: x = LN(x+y)*g+b, write fp32 + bf16 ----------------
__global__ __launch_bounds__(64) void ln_residual(
    const float* __restrict__ x, const float* __restrict__ y,
    const float* __restrict__ g, const float* __restrict__ b,
    float* __restrict__ xout, u16* __restrict__ xbout)
{
  long row = blockIdx.x;
  int t = threadIdx.x;
  const float* xr = x + row * DM;
  const float* yr = y + row * DM;
  float v[12];
  float sum = 0.f, sq = 0.f;
  #pragma unroll
  for (int j = 0; j < 3; j++) {
    int d = j * 256 + t * 4;
    float4 a = *(const float4*)(xr + d);
    float4 c = *(const float4*)(yr + d);
    float z0 = a.x + c.x, z1 = a.y + c.y, z2 = a.z + c.z, z3 = a.w + c.w;
    v[j*4+0] = z0; v[j*4+1] = z1; v[j*4+2] = z2; v[j*4+3] = z3;
    sum += z0 + z1 + z2 + z3;
    sq  += z0*z0 + z1*z1 + z2*z2 + z3*z3;
  }
  #pragma unroll
  for (int m = 1; m < 64; m <<= 1) {
    sum += __shfl_xor(sum, m, 64);
    sq  += __shfl_xor(sq,  m, 64);
  }
  float mu = sum * (1.f / 768.f);
  float var = sq * (1.f / 768.f) - mu * mu;
  float rstd = rsqrtf(var + 1e-5f);
  #pragma unroll
  for (int j = 0; j < 3; j++) {
    int d = j * 256 + t * 4;
    float4 gg = *(const float4*)(g + d);
    float4 bb = *(const float4*)(b + d);
    float z0 = (v[j*4+0] - mu) * rstd * gg.x + bb.x;
    float z1 = (v[j*4+1] - mu) * rstd * gg.y + bb.y;
    float z2 = (v[j*4+2] - mu) * rstd * gg.z + bb.z;
    float z3 = (v[j*4+3] - mu) * rstd * gg.w + bb.w;
    float4 fz; fz.x = z0; fz.y = z1; fz.z = z2; fz.w = z3;
    *(float4*)(xout + row * DM + d) = fz;
    uint2 pk;
    pk.x = f2bf(z0) | ((unsigned)f2bf(z1) << 16);
    pk.y = f2bf(z2) | ((unsigned)f2bf(z3) << 16);
    *(uint2*)(xbout + row * DM + d) = pk;
  }
}

// ---------------- classifier: out[b][c] = x[b,0,:] . cls_w[:,c] + cls_b[c] ----------------
__global__ __launch_bounds__(64) void classifier_kernel(
    const float* __restrict__ x, const float* __restrict__ w,
    const float* __restrict__ bias, float* __restrict__ out)
{
  int bc = blockIdx.x;
  int b = bc / NCLS, c = bc % NCLS;
  const float* xr = x + (long)b * SEQ * DM;   // l = 0
  float sum = 0.f;
  for (int d = threadIdx.x; d < DM; d += 64)
    sum += xr[d] * w[d * NCLS + c];
  #pragma unroll
  for (int m = 1; m < 64; m <<= 1) sum += __shfl_xor(sum, m, 64);
  if (threadIdx.x == 0) out[bc] = sum + bias[c];
}

extern "C" void kernel_launch(void* const* d_in, const int* in_sizes, int n_in,
                              void* d_out, int out_size, void* d_ws, size_t ws_size,
                              hipStream_t stream)
{
  const int*   ids  = (const int*)d_in[0];
  const int*   mask = (const int*)d_in[1];
  const float* emb  = (const float*)d_in[2];
  const float* wq   = (const float*)d_in[3];
  const float* bq   = (const float*)d_in[4];
  const float* wk   = (const float*)d_in[5];
  const float* bk   = (const float*)d_in[6];
  const float* wv   = (const float*)d_in[7];
  const float* bv   = (const float*)d_in[8];
  const float* wo   = (const float*)d_in[9];
  const float* bo   = (const float*)d_in[10];
  const float* ln1g = (const float*)d_in[11];
  const float* ln1b = (const float*)d_in[12];
  const float* w1   = (const float*)d_in[13];
  const float* b1   = (const float*)d_in[14];
  const float* w2   = (const float*)d_in[15];
  const float* b2   = (const float*)d_in[16];
  const float* ln2g = (const float*)d_in[17];
  const float* ln2b = (const float*)d_in[18];
  const float* clsw = (const float*)d_in[19];
  const float* clsb = (const float*)d_in[20];

  char* ws = (char*)d_ws;
  size_t off = 0;
  auto alloc = [&](size_t bytes) -> void* {
    void* p = ws + off;
    off += (bytes + 255) & ~(size_t)255;
    return p;
  };
  float* X     = (float*)alloc((size_t)NTOK * DM * 4);
  u16*   XB    = (u16*)  alloc((size_t)NTOK * DM * 2);
  float* QKV   = (float*)alloc((size_t)NTOK * 2304 * 4);
  u16*   CTXB  = (u16*)  alloc((size_t)NTOK * DM * 2);
  u16*   H1B   = (u16*)  alloc((size_t)NTOK * FD * 2);
  u16*   WQKVT = (u16*)  alloc((size_t)NLAYER * 2304 * 768 * 2);
  u16*   WOT   = (u16*)  alloc((size_t)NLAYER * 768 * 768 * 2);
  u16*   W1T   = (u16*)  alloc((size_t)NLAYER * 3072 * 768 * 2);
  u16*   W2T   = (u16*)  alloc((size_t)NLAYER * 768 * 3072 * 2);
  float* QKVB  = (float*)alloc((size_t)NLAYER * 2304 * 4);
  // aliases into the (dead-by-then) QKV buffer:
  float* FF2  = QKV;                                          // [NTOK][768]
  float* ATTN = (float*)((char*)QKV + (size_t)NTOK * DM * 4); // [NTOK][768]

  dim3 tb(32, 8);
  transpose_f32_bf16<<<dim3(24, 24, 6), tb, 0, stream>>>(wq, WQKVT, 768, 768, 768L*768, 2304L*768, 0);
  transpose_f32_bf16<<<dim3(24, 24, 6), tb, 0, stream>>>(wk, WQKVT, 768, 768, 768L*768, 2304L*768, 768L*768);
  transpose_f32_bf16<<<dim3(24, 24, 6), tb, 0, stream>>>(wv, WQKVT, 768, 768, 768L*768, 2304L*768, 1536L*768);
  transpose_f32_bf16<<<dim3(24, 24, 6), tb, 0, stream>>>(wo, WOT, 768, 768, 768L*768, 768L*768, 0);
  transpose_f32_bf16<<<dim3(96, 24, 6), tb, 0, stream>>>(w1, W1T, 768, 3072, 768L*3072, 3072L*768, 0);
  transpose_f32_bf16<<<dim3(24, 96, 6), tb, 0, stream>>>(w2, W2T, 3072, 768, 3072L*768, 768L*3072, 0);
  concat_bias<<<(NLAYER * 2304 + 255) / 256, 256, 0, stream>>>(bq, bk, bv, QKVB);
  embed_kernel<<<NTOK * DM / 1024, 256, 0, stream>>>(ids, emb, X, XB);

  for (int L = 0; L < NLAYER; L++) {
    gemm_bt<<<dim3(64, 18), 256, 0, stream>>>(
        XB, WQKVT + (size_t)L * 2304 * 768, QKVB + L * 2304, QKV, nullptr, 2304, 768, 0);
    attention_kernel<<<96 * 16, 64, 0, stream>>>(QKV, mask, CTXB);
    gemm_bt<<<dim3(64, 6), 256, 0, stream>>>(
        CTXB, WOT + (size_t)L * 768 * 768, bo + L * 768, ATTN, nullptr, 768, 768, 0);
    ln_residual<<<NTOK, 64, 0, stream>>>(X, ATTN, ln1g + L * 768, ln1b + L * 768, X, XB);
    gemm_bt<<<dim3(64, 24), 256, 0, stream>>>(
        XB, W1T + (size_t)L * 3072 * 768, b1 + L * 3072, nullptr, H1B, 3072, 768, 1);
    gemm_bt<<<dim3(64, 6), 256, 0, stream>>>(
        H1B, W2T + (size_t)L * 768 * 3072, b2 + L * 768, FF2, nullptr, 768, 3072, 0);
    ln_residual<<<NTOK, 64, 0, stream>>>(X, FF2, ln2g + L * 768, ln2b + L * 768, X, XB);
  }
  classifier_kernel<<<80, 64, 0, stream>>>(X, clsw, clsb, (float*)d_out);
}

// Round 2
// 2496.735 us; speedup vs baseline: 5.1324x; 5.1324x over previous
//
#include <hip/hip_runtime.h>
#include <stdint.h>

typedef unsigned short u16;
typedef __bf16 bf16x8 __attribute__((ext_vector_type(8)));
typedef float f32x4 __attribute__((ext_vector_type(4)));

#define NLAYER 6
#define DM 768
#define NH 12
#define FD 3072
#define NCLS 10
#define BATCH 8
#define SEQ 1024
#define NTOK (BATCH*SEQ)
#define PST 72   // padded LDS row stride (u16): bank = (4*row+4*quad)%32 -> 2-way (free)

__device__ __forceinline__ u16 f2bf(float f) {
  union { float f; unsigned u; } v; v.f = f;
  unsigned u = v.u;
  return (u16)((u + 0x7fffu + ((u >> 16) & 1u)) >> 16);
}

__device__ __forceinline__ void async16(const void* g, void* l) {
  __builtin_amdgcn_global_load_lds(
      (__attribute__((address_space(1))) void*)(void*)g,
      (__attribute__((address_space(3))) void*)l, 16, 0, 0);
}

// ---------------- transpose fp32 [R][C] -> bf16 [C][R], per-layer z ----------------
__global__ __launch_bounds__(256) void transpose_f32_bf16(
    const float* __restrict__ in, u16* __restrict__ out,
    int R, int C, long inLS, long outLS, long outOff)
{
  __shared__ float tile[32][33];
  const float* inp = in + (long)blockIdx.z * inLS;
  u16* outp = out + (long)blockIdx.z * outLS + outOff;
  int c0 = blockIdx.x * 32, r0 = blockIdx.y * 32;
  int tx = threadIdx.x, ty = threadIdx.y;
  #pragma unroll
  for (int j = 0; j < 32; j += 8)
    tile[ty + j][tx] = inp[(long)(r0 + ty + j) * C + c0 + tx];
  __syncthreads();
  #pragma unroll
  for (int j = 0; j < 32; j += 8)
    outp[(long)(c0 + ty + j) * R + r0 + tx] = f2bf(tile[tx][ty + j]);
}

// ---------------- concat q/k/v biases into [NLAYER][2304] ----------------
__global__ void concat_bias(const float* __restrict__ bq, const float* __restrict__ bk,
                            const float* __restrict__ bv, float* __restrict__ qkvb)
{
  int i = blockIdx.x * 256 + threadIdx.x;
  if (i >= NLAYER * 2304) return;
  int layer = i / 2304, c = i % 2304;
  float v;
  if (c < 768) v = bq[layer * 768 + c];
  else if (c < 1536) v = bk[layer * 768 + c - 768];
  else v = bv[layer * 768 + c - 1536];
  qkvb[i] = v;
}

// ---------------- embedding + sinusoidal PE -> x fp32 + x bf16 ----------------
__global__ __launch_bounds__(256) void embed_kernel(
    const int* __restrict__ ids, const float* __restrict__ emb,
    float* __restrict__ x, u16* __restrict__ xb)
{
  int e = (blockIdx.x * 256 + threadIdx.x) * 4;
  int d = e % DM;
  int tok = e / DM;
  int l = tok % SEQ;
  int id = ids[tok];
  float4 em = *(const float4*)(emb + (long)id * DM + d);
  const float cexp = -9.210340371976184f / 768.f;   // -ln(10000)/D
  float div0 = __expf((float)d * cexp);
  float div1 = __expf((float)(d + 2) * cexp);
  float a0 = (float)l * div0, a1 = (float)l * div1;
  em.x += sinf(a0); em.y += cosf(a0);
  em.z += sinf(a1); em.w += cosf(a1);
  *(float4*)(x + e) = em;
  uint2 pk;
  pk.x = f2bf(em.x) | ((unsigned)f2bf(em.y) << 16);
  pk.y = f2bf(em.z) | ((unsigned)f2bf(em.w) << 16);
  *(uint2*)(xb + e) = pk;
}

// ---------------- bf16 MFMA GEMM: C[M][N] = A[M][K] @ BT[N][K]^T + bias ----------------
__global__ __launch_bounds__(256) void gemm_bt(
    const u16* __restrict__ A, const u16* __restrict__ BT,
    const float* __restrict__ bias,
    float* __restrict__ Cf, u16* __restrict__ Cb,
    int N, int K, int relu)
{
  __shared__ u16 As[128 * 32];
  __shared__ u16 Bs[128 * 32];
  int tid = threadIdx.x;
  int wave = tid >> 6, lane = tid & 63;
  int wm = (wave >> 1) * 64, wn = (wave & 1) * 64;
  int row16 = lane & 15, quad = lane >> 4;
  long mBase = (long)blockIdx.x * 128;
  long nBase = (long)blockIdx.y * 128;
  int arow = lane >> 2;
  int acol = (lane & 3) * 8;

  f32x4 acc[4][4] = {};

  for (int k0 = 0; k0 < K; k0 += 32) {
    __syncthreads();
    int c0 = wave * 2;
    async16(A  + (mBase + c0 * 16      + arow) * (long)K + k0 + acol, As + c0 * 512);
    async16(A  + (mBase + c0 * 16 + 16 + arow) * (long)K + k0 + acol, As + (c0 + 1) * 512);
    async16(BT + (nBase + c0 * 16      + arow) * (long)K + k0 + acol, Bs + c0 * 512);
    async16(BT + (nBase + c0 * 16 + 16 + arow) * (long)K + k0 + acol, Bs + (c0 + 1) * 512);
    __syncthreads();

    bf16x8 aF[4], bF[4];
    #pragma unroll
    for (int i = 0; i < 4; i++)
      aF[i] = *(const bf16x8*)(As + (wm + i * 16 + row16) * 32 + quad * 8);
    #pragma unroll
    for (int j = 0; j < 4; j++)
      bF[j] = *(const bf16x8*)(Bs + (wn + j * 16 + row16) * 32 + quad * 8);
    #pragma unroll
    for (int i = 0; i < 4; i++)
      #pragma unroll
      for (int j = 0; j < 4; j++)
        acc[i][j] = __builtin_amdgcn_mfma_f32_16x16x32_bf16(aF[i], bF[j], acc[i][j], 0, 0, 0);
  }

  #pragma unroll
  for (int j = 0; j < 4; j++) {
    long gn = nBase + wn + j * 16 + row16;
    float bv = bias[gn];
    #pragma unroll
    for (int i = 0; i < 4; i++) {
      #pragma unroll
      for (int r = 0; r < 4; r++) {
        long gm = mBase + wm + i * 16 + quad * 4 + r;
        float v = acc[i][j][r] + bv;
        if (relu) v = fmaxf(v, 0.f);
        long idx = gm * (long)N + gn;
        if (Cf) Cf[idx] = v;
        if (Cb) Cb[idx] = f2bf(v);
      }
    }
  }
}

// ---------------- V transpose: qkv bf16 [tok][2304] V-part -> VT[bh][dk=64][seq=1024] ----------------
__global__ __launch_bounds__(256) void v_transpose(
    const u16* __restrict__ qkvb, u16* __restrict__ vtg)
{
  __shared__ __align__(16) u16 T[64 * PST];
  int tid = threadIdx.x;
  int st = blockIdx.x, bh = blockIdx.y;
  int b = bh / NH, h = bh - b * NH;
  int row = tid >> 2, col = (tid & 3) * 16;
  const u16* src = qkvb + ((long)b * SEQ + st * 64 + row) * 2304 + 1536 + h * 64 + col;
  *(uint4*)&T[row * PST + col]     = *(const uint4*)src;
  *(uint4*)&T[row * PST + col + 8] = *(const uint4*)(src + 8);
  __syncthreads();
  u16 tmp[16];
  #pragma unroll
  for (int j = 0; j < 16; j++) tmp[j] = T[(col + j) * PST + row];
  u16* dst = vtg + ((long)bh * 64 + row) * SEQ + st * 64 + col;
  *(uint4*)dst       = *(const uint4*)&tmp[0];
  *(uint4*)(dst + 8) = *(const uint4*)&tmp[8];
}

// ---------------- MFMA flash attention: block = (qtile 64 rows, bh), 4 waves x 16 q-rows ----------------
__global__ __launch_bounds__(256) void attention_mfma(
    const u16* __restrict__ qkvb, const int* __restrict__ mask,
    const u16* __restrict__ vtg, u16* __restrict__ ctxb)
{
  __shared__ __align__(16) u16 Kb[64 * PST];
  __shared__ __align__(16) u16 Vt[64 * PST];
  __shared__ __align__(16) u16 Pl[4][16 * PST];
  __shared__ float negs[64];
  int tid = threadIdx.x;
  int wave = tid >> 6, lane = tid & 63;
  int l15 = lane & 15, quad = lane >> 4;
  int qt = blockIdx.x, bh = blockIdx.y;
  int b = bh / NH, h = bh - b * NH;
  long qtok = (long)b * SEQ + qt * 64;

  // Q fragments for this wave's 16 q-rows (A layout: m=lane&15, k=quad*8+j)
  bf16x8 aQ[2];
  {
    const u16* qp = qkvb + (qtok + wave * 16 + l15) * 2304 + h * 64 + quad * 8;
    aQ[0] = *(const bf16x8*)qp;
    aQ[1] = *(const bf16x8*)(qp + 32);
  }
  f32x4 oacc[4] = {};
  float mrow[4] = {-3e38f, -3e38f, -3e38f, -3e38f};
  float lrow[4] = {0.f, 0.f, 0.f, 0.f};

  int srow = tid >> 2, scol = (tid & 3) * 16;
  const u16* kgp = qkvb + ((long)b * SEQ) * 2304 + 768 + h * 64;
  const u16* vgp = vtg + ((long)bh * 64 + srow) * SEQ;

  for (int kt = 0; kt < 16; kt++) {
    __syncthreads();
    const u16* kr = kgp + (long)(kt * 64 + srow) * 2304 + scol;
    *(uint4*)&Kb[srow * PST + scol]     = *(const uint4*)kr;
    *(uint4*)&Kb[srow * PST + scol + 8] = *(const uint4*)(kr + 8);
    const u16* vr = vgp + kt * 64 + scol;
    *(uint4*)&Vt[srow * PST + scol]     = *(const uint4*)vr;
    *(uint4*)&Vt[srow * PST + scol + 8] = *(const uint4*)(vr + 8);
    if (tid < 64) negs[tid] = (mask[(long)b * SEQ + kt * 64 + tid] == 0) ? -1e9f : 0.f;
    __syncthreads();

    // S strip = Q(16 rows) @ K^T(64 keys): B operand = K[key][dk] natural layout
    f32x4 sa[4] = {};
    #pragma unroll
    for (int kc = 0; kc < 2; kc++) {
      #pragma unroll
      for (int n = 0; n < 4; n++) {
        bf16x8 bk = *(const bf16x8*)&Kb[(n * 16 + l15) * PST + kc * 32 + quad * 8];
        sa[n] = __builtin_amdgcn_mfma_f32_16x16x32_bf16(aQ[kc], bk, sa[n], 0, 0, 0);
      }
    }
    float ng[4];
    #pragma unroll
    for (int n = 0; n < 4; n++) ng[n] = negs[n * 16 + l15];
    float pv[4][4], al[4];
    #pragma unroll
    for (int r = 0; r < 4; r++) {
      float s0 = sa[0][r] * 0.125f + ng[0];
      float s1 = sa[1][r] * 0.125f + ng[1];
      float s2 = sa[2][r] * 0.125f + ng[2];
      float s3 = sa[3][r] * 0.125f + ng[3];
      float mx = fmaxf(fmaxf(s0, s1), fmaxf(s2, s3));
      mx = fmaxf(mx, __shfl_xor(mx, 1, 64));
      mx = fmaxf(mx, __shfl_xor(mx, 2, 64));
      mx = fmaxf(mx, __shfl_xor(mx, 4, 64));
      mx = fmaxf(mx, __shfl_xor(mx, 8, 64));
      float mn = fmaxf(mrow[r], mx);
      float a = __expf(mrow[r] - mn);
      mrow[r] = mn;
      float p0 = __expf(s0 - mn), p1 = __expf(s1 - mn);
      float p2 = __expf(s2 - mn), p3 = __expf(s3 - mn);
      pv[0][r] = p0; pv[1][r] = p1; pv[2][r] = p2; pv[3][r] = p3;
      float rs = p0 + p1 + p2 + p3;
      rs += __shfl_xor(rs, 1, 64);
      rs += __shfl_xor(rs, 2, 64);
      rs += __shfl_xor(rs, 4, 64);
      rs += __shfl_xor(rs, 8, 64);
      lrow[r] = lrow[r] * a + rs;
      al[r] = a;
    }
    #pragma unroll
    for (int d = 0; d < 4; d++)
      #pragma unroll
      for (int r = 0; r < 4; r++)
        oacc[d][r] *= al[r];

    // P: C-layout -> LDS -> A-layout (per-wave strip, no barrier needed)
    u16* pw = &Pl[wave][0];
    #pragma unroll
    for (int n = 0; n < 4; n++)
      #pragma unroll
      for (int r = 0; r < 4; r++)
        pw[(quad * 4 + r) * PST + n * 16 + l15] = f2bf(pv[n][r]);
    #pragma unroll
    for (int kc = 0; kc < 2; kc++) {
      bf16x8 ap = *(const bf16x8*)&pw[l15 * PST + kc * 32 + quad * 8];
      #pragma unroll
      for (int d = 0; d < 4; d++) {
        bf16x8 bv = *(const bf16x8*)&Vt[(d * 16 + l15) * PST + kc * 32 + quad * 8];
        oacc[d] = __builtin_amdgcn_mfma_f32_16x16x32_bf16(ap, bv, oacc[d], 0, 0, 0);
      }
    }
  }

  // epilogue: normalize, linearize through LDS, coalesced 128B stores
  float inv[4];
  #pragma unroll
  for (int r = 0; r < 4; r++) inv[r] = 1.f / lrow[r];
  u16* pw = &Pl[wave][0];
  #pragma unroll
  for (int d = 0; d < 4; d++)
    #pragma unroll
    for (int r = 0; r < 4; r++)
      pw[(quad * 4 + r) * PST + d * 16 + l15] = f2bf(oacc[d][r] * inv[r]);
  __syncthreads();
  int orow = lane >> 2, ocol = (lane & 3) * 16;
  u16* og = ctxb + (qtok + wave * 16 + orow) * DM + h * 64 + ocol;
  *(uint4*)og       = *(const uint4*)&pw[orow * PST + ocol];
  *(uint4*)(og + 8) = *(const uint4*)&pw[orow * PST + ocol + 8];
}

// ---------------- fused residual + layernorm ----------------
__global__ __launch_bounds__(64) void ln_residual(
    const float* __restrict__ x, const float* __restrict__ y,
    const float* __restrict__ g, const float* __restrict__ b,
    float* __restrict__ xout, u16* __restrict__ xbout)
{
  long row = blockIdx.x;
  int t = threadIdx.x;
  const float* xr = x + row * DM;
  const float* yr = y + row * DM;
  float v[12];
  float sum = 0.f, sq = 0.f;
  #pragma unroll
  for (int j = 0; j < 3; j++) {
    int d = j * 256 + t * 4;
    float4 a = *(const float4*)(xr + d);
    float4 c = *(const float4*)(yr + d);
    float z0 = a.x + c.x, z1 = a.y + c.y, z2 = a.z + c.z, z3 = a.w + c.w;
    v[j*4+0] = z0; v[j*4+1] = z1; v[j*4+2] = z2; v[j*4+3] = z3;
    sum += z0 + z1 + z2 + z3;
    sq  += z0*z0 + z1*z1 + z2*z2 + z3*z3;
  }
  #pragma unroll
  for (int m = 1; m < 64; m <<= 1) {
    sum += __shfl_xor(sum, m, 64);
    sq  += __shfl_xor(sq,  m, 64);
  }
  float mu = sum * (1.f / 768.f);
  float var = sq * (1.f / 768.f) - mu * mu;
  float rstd = rsqrtf(var + 1e-5f);
  #pragma unroll
  for (int j = 0; j < 3; j++) {
    int d = j * 256 + t * 4;
    float4 gg = *(const float4*)(g + d);
    float4 bb = *(const float4*)(b + d);
    float z0 = (v[j*4+0] - mu) * rstd * gg.x + bb.x;
    float z1 = (v[j*4+1] - mu) * rstd * gg.y + bb.y;
    float z2 = (v[j*4+2] - mu) * rstd * gg.z + bb.z;
    float z3 = (v[j*4+3] - mu) * rstd * gg.w + bb.w;
    float4 fz; fz.x = z0; fz.y = z1; fz.z = z2; fz.w = z3;
    *(float4*)(xout + row * DM + d) = fz;
    uint2 pk;
    pk.x = f2bf(z0) | ((unsigned)f2bf(z1) << 16);
    pk.y = f2bf(z2) | ((unsigned)f2bf(z3) << 16);
    *(uint2*)(xbout + row * DM + d) = pk;
  }
}

// ---------------- classifier ----------------
__global__ __launch_bounds__(64) void classifier_kernel(
    const float* __restrict__ x, const float* __restrict__ w,
    const float* __restrict__ bias, float* __restrict__ out)
{
  int bc = blockIdx.x;
  int b = bc / NCLS, c = bc % NCLS;
  const float* xr = x + (long)b * SEQ * DM;
  float sum = 0.f;
  for (int d = threadIdx.x; d < DM; d += 64)
    sum += xr[d] * w[d * NCLS + c];
  #pragma unroll
  for (int m = 1; m < 64; m <<= 1) sum += __shfl_xor(sum, m, 64);
  if (threadIdx.x == 0) out[bc] = sum + bias[c];
}

extern "C" void kernel_launch(void* const* d_in, const int* in_sizes, int n_in,
                              void* d_out, int out_size, void* d_ws, size_t ws_size,
                              hipStream_t stream)
{
  const int*   ids  = (const int*)d_in[0];
  const int*   mask = (const int*)d_in[1];
  const float* emb  = (const float*)d_in[2];
  const float* wq   = (const float*)d_in[3];
  const float* bq   = (const float*)d_in[4];
  const float* wk   = (const float*)d_in[5];
  const float* bk   = (const float*)d_in[6];
  const float* wv   = (const float*)d_in[7];
  const float* bv   = (const float*)d_in[8];
  const float* wo   = (const float*)d_in[9];
  const float* bo   = (const float*)d_in[10];
  const float* ln1g = (const float*)d_in[11];
  const float* ln1b = (const float*)d_in[12];
  const float* w1   = (const float*)d_in[13];
  const float* b1   = (const float*)d_in[14];
  const float* w2   = (const float*)d_in[15];
  const float* b2   = (const float*)d_in[16];
  const float* ln2g = (const float*)d_in[17];
  const float* ln2b = (const float*)d_in[18];
  const float* clsw = (const float*)d_in[19];
  const float* clsb = (const float*)d_in[20];

  char* ws = (char*)d_ws;
  size_t off = 0;
  auto alloc = [&](size_t bytes) -> void* {
    void* p = ws + off;
    off += (bytes + 255) & ~(size_t)255;
    return p;
  };
  float* X     = (float*)alloc((size_t)NTOK * DM * 4);
  u16*   XB    = (u16*)  alloc((size_t)NTOK * DM * 2);
  u16*   QKVB16= (u16*)  alloc((size_t)NTOK * 2304 * 2);
  u16*   VT    = (u16*)  alloc((size_t)96 * 64 * SEQ * 2);
  u16*   CTXB  = (u16*)  alloc((size_t)NTOK * DM * 2);
  u16*   H1B   = (u16*)  alloc((size_t)NTOK * FD * 2);
  float* SCR   = (float*)alloc((size_t)NTOK * DM * 4);   // attn-out, then ff2-out
  u16*   WQKVT = (u16*)  alloc((size_t)NLAYER * 2304 * 768 * 2);
  u16*   WOT   = (u16*)  alloc((size_t)NLAYER * 768 * 768 * 2);
  u16*   W1T   = (u16*)  alloc((size_t)NLAYER * 3072 * 768 * 2);
  u16*   W2T   = (u16*)  alloc((size_t)NLAYER * 768 * 3072 * 2);
  float* QKVB  = (float*)alloc((size_t)NLAYER * 2304 * 4);

  dim3 tb(32, 8);
  transpose_f32_bf16<<<dim3(24, 24, 6), tb, 0, stream>>>(wq, WQKVT, 768, 768, 768L*768, 2304L*768, 0);
  transpose_f32_bf16<<<dim3(24, 24, 6), tb, 0, stream>>>(wk, WQKVT, 768, 768, 768L*768, 2304L*768, 768L*768);
  transpose_f32_bf16<<<dim3(24, 24, 6), tb, 0, stream>>>(wv, WQKVT, 768, 768, 768L*768, 2304L*768, 1536L*768);
  transpose_f32_bf16<<<dim3(24, 24, 6), tb, 0, stream>>>(wo, WOT, 768, 768, 768L*768, 768L*768, 0);
  transpose_f32_bf16<<<dim3(96, 24, 6), tb, 0, stream>>>(w1, W1T, 768, 3072, 768L*3072, 3072L*768, 0);
  transpose_f32_bf16<<<dim3(24, 96, 6), tb, 0, stream>>>(w2, W2T, 3072, 768, 3072L*768, 768L*3072, 0);
  concat_bias<<<(NLAYER * 2304 + 255) / 256, 256, 0, stream>>>(bq, bk, bv, QKVB);
  embed_kernel<<<NTOK * DM / 1024, 256, 0, stream>>>(ids, emb, X, XB);

  for (int L = 0; L < NLAYER; L++) {
    gemm_bt<<<dim3(64, 18), 256, 0, stream>>>(
        XB, WQKVT + (size_t)L * 2304 * 768, QKVB + L * 2304, nullptr, QKVB16, 2304, 768, 0);
    v_transpose<<<dim3(16, 96), 256, 0, stream>>>(QKVB16, VT);
    attention_mfma<<<dim3(16, 96), 256, 0, stream>>>(QKVB16, mask, VT, CTXB);
    gemm_bt<<<dim3(64, 6), 256, 0, stream>>>(
        CTXB, WOT + (size_t)L * 768 * 768, bo + L * 768, SCR, nullptr, 768, 768, 0);
    ln_residual<<<NTOK, 64, 0, stream>>>(X, SCR, ln1g + L * 768, ln1b + L * 768, X, XB);
    gemm_bt<<<dim3(64, 24), 256, 0, stream>>>(
        XB, W1T + (size_t)L * 3072 * 768, b1 + L * 3072, nullptr, H1B, 3072, 768, 1);
    gemm_bt<<<dim3(64, 6), 256, 0, stream>>>(
        H1B, W2T + (size_t)L * 768 * 3072, b2 + L * 768, SCR, nullptr, 768, 3072, 0);
    ln_residual<<<NTOK, 64, 0, stream>>>(X, SCR, ln2g + L * 768, ln2b + L * 768, X, XB);
  }
  classifier_kernel<<<80, 64, 0, stream>>>(X, clsw, clsb, (float*)d_out);
}

// Round 3
// 2021.579 us; speedup vs baseline: 6.3387x; 1.2350x over previous
//
#include <hip/hip_runtime.h>
#include <stdint.h>

typedef unsigned short u16;
typedef __bf16 bf16x8 __attribute__((ext_vector_type(8)));
typedef float f32x4 __attribute__((ext_vector_type(4)));

#define NLAYER 6
#define DM 768
#define NH 12
#define FD 3072
#define NCLS 10
#define BATCH 8
#define SEQ 1024
#define NTOK (BATCH*SEQ)
#define PST 72   // padded stride for the P strip (C->A round trip)

__device__ __forceinline__ u16 f2bf(float f) {
  union { float f; unsigned u; } v; v.f = f;
  unsigned u = v.u;
  return (u16)((u + 0x7fffu + ((u >> 16) & 1u)) >> 16);
}

__device__ __forceinline__ void async16(const void* g, void* l) {
  __builtin_amdgcn_global_load_lds(
      (__attribute__((address_space(1))) void*)(void*)g,
      (__attribute__((address_space(3))) void*)l, 16, 0, 0);
}

// ---------------- transpose fp32 [R][C] -> bf16 [C][R], per-layer z ----------------
__global__ __launch_bounds__(256) void transpose_f32_bf16(
    const float* __restrict__ in, u16* __restrict__ out,
    int R, int C, long inLS, long outLS, long outOff)
{
  __shared__ float tile[32][33];
  const float* inp = in + (long)blockIdx.z * inLS;
  u16* outp = out + (long)blockIdx.z * outLS + outOff;
  int c0 = blockIdx.x * 32, r0 = blockIdx.y * 32;
  int tx = threadIdx.x, ty = threadIdx.y;
  #pragma unroll
  for (int j = 0; j < 32; j += 8)
    tile[ty + j][tx] = inp[(long)(r0 + ty + j) * C + c0 + tx];
  __syncthreads();
  #pragma unroll
  for (int j = 0; j < 32; j += 8)
    outp[(long)(c0 + ty + j) * R + r0 + tx] = f2bf(tile[tx][ty + j]);
}

// ---------------- concat q/k/v biases into [NLAYER][2304] ----------------
__global__ void concat_bias(const float* __restrict__ bq, const float* __restrict__ bk,
                            const float* __restrict__ bv, float* __restrict__ qkvb)
{
  int i = blockIdx.x * 256 + threadIdx.x;
  if (i >= NLAYER * 2304) return;
  int layer = i / 2304, c = i % 2304;
  float v;
  if (c < 768) v = bq[layer * 768 + c];
  else if (c < 1536) v = bk[layer * 768 + c - 768];
  else v = bv[layer * 768 + c - 1536];
  qkvb[i] = v;
}

// ---------------- embedding + sinusoidal PE -> x fp32 + x bf16 ----------------
__global__ __launch_bounds__(256) void embed_kernel(
    const int* __restrict__ ids, const float* __restrict__ emb,
    float* __restrict__ x, u16* __restrict__ xb)
{
  int e = (blockIdx.x * 256 + threadIdx.x) * 4;
  int d = e % DM;
  int tok = e / DM;
  int l = tok % SEQ;
  int id = ids[tok];
  float4 em = *(const float4*)(emb + (long)id * DM + d);
  const float cexp = -9.210340371976184f / 768.f;   // -ln(10000)/D
  float div0 = __expf((float)d * cexp);
  float div1 = __expf((float)(d + 2) * cexp);
  float a0 = (float)l * div0, a1 = (float)l * div1;
  em.x += sinf(a0); em.y += cosf(a0);
  em.z += sinf(a1); em.w += cosf(a1);
  *(float4*)(x + e) = em;
  uint2 pk;
  pk.x = f2bf(em.x) | ((unsigned)f2bf(em.y) << 16);
  pk.y = f2bf(em.z) | ((unsigned)f2bf(em.w) << 16);
  *(uint2*)(xb + e) = pk;
}

// ---------------- bf16 MFMA GEMM: C[M][N] = A[M][K] @ BT[N][K]^T + bias ----------------
// TM x 128 tile, BK=64, XOR-8 swizzled LDS (conflict-free b128 frag reads),
// global_load_lds x16 staging. Optional transposed-V epilogue for the QKV GEMM.
template<int TM>
__global__ __launch_bounds__(256) void gemm_bt(
    const u16* __restrict__ A, const u16* __restrict__ BT,
    const float* __restrict__ bias,
    float* __restrict__ Cf, u16* __restrict__ Cb, u16* __restrict__ VTout,
    int N, int K, int relu)
{
  constexpr int MI  = TM / 32;     // A fragments per wave
  constexpr int ACH = TM / 8;      // A chunks (1 KB each)
  constexpr int NCH = ACH + 16;    // + B chunks
  __shared__ __align__(16) u16 As[TM * 64];
  __shared__ __align__(16) u16 Bs[128 * 64];
  int tid = threadIdx.x;
  int wave = tid >> 6, lane = tid & 63;
  int wm = (wave >> 1) * (TM / 2);
  int wn = (wave & 1) * 64;
  int l15 = lane & 15, quad = lane >> 4;
  long mBase = (long)blockIdx.x * TM;
  long nBase = (long)blockIdx.y * 128;
  int r8 = lane >> 3;
  int g8 = ((lane & 7) ^ r8) * 8;   // swizzled source column group

  const u16* gsrc[NCH / 4];
  u16* ldst[NCH / 4];
  #pragma unroll
  for (int idx = 0; idx < NCH / 4; idx++) {
    int c = wave + idx * 4;
    if (c < ACH) {
      gsrc[idx] = A + (mBase + c * 8 + r8) * (long)K + g8;
      ldst[idx] = As + c * 512;
    } else {
      int cc = c - ACH;
      gsrc[idx] = BT + (nBase + cc * 8 + r8) * (long)K + g8;
      ldst[idx] = Bs + cc * 512;
    }
  }
  int sw = l15 & 7;
  int aoff[2], boff[2];
  #pragma unroll
  for (int kc = 0; kc < 2; kc++) {
    aoff[kc] = (wm + l15) * 64 + 8 * ((kc * 4 + quad) ^ sw);
    boff[kc] = (wn + l15) * 64 + 8 * ((kc * 4 + quad) ^ sw);
  }

  f32x4 acc[MI][4] = {};

  for (int k0 = 0; k0 < K; k0 += 64) {
    __syncthreads();
    #pragma unroll
    for (int idx = 0; idx < NCH / 4; idx++)
      async16(gsrc[idx] + k0, ldst[idx]);
    __syncthreads();
    #pragma unroll
    for (int kc = 0; kc < 2; kc++) {
      bf16x8 aF[MI], bF[4];
      #pragma unroll
      for (int i = 0; i < MI; i++) aF[i] = *(const bf16x8*)(As + aoff[kc] + i * 1024);
      #pragma unroll
      for (int j = 0; j < 4; j++)  bF[j] = *(const bf16x8*)(Bs + boff[kc] + j * 1024);
      #pragma unroll
      for (int i = 0; i < MI; i++)
        #pragma unroll
        for (int j = 0; j < 4; j++)
          acc[i][j] = __builtin_amdgcn_mfma_f32_16x16x32_bf16(aF[i], bF[j], acc[i][j], 0, 0, 0);
    }
  }

  #pragma unroll
  for (int j = 0; j < 4; j++) {
    long gn = nBase + wn + j * 16 + l15;
    float bv = bias[gn];
    bool isV = (VTout != nullptr) && (gn >= 1536);
    #pragma unroll
    for (int i = 0; i < MI; i++) {
      long gm0 = mBase + wm + i * 16 + quad * 4;
      if (isV) {
        int h = ((int)gn - 1536) >> 6, dk = (int)gn & 63;
        int bb = (int)(gm0 >> 10), seq = (int)(gm0 & 1023);
        u16* dst = VTout + (((long)(bb * NH + h) * 64 + dk) << 10) + seq;
        uint2 pk;
        pk.x = f2bf(acc[i][j][0] + bv) | ((unsigned)f2bf(acc[i][j][1] + bv) << 16);
        pk.y = f2bf(acc[i][j][2] + bv) | ((unsigned)f2bf(acc[i][j][3] + bv) << 16);
        *(uint2*)dst = pk;
      } else {
        #pragma unroll
        for (int r = 0; r < 4; r++) {
          float v = acc[i][j][r] + bv;
          if (relu) v = fmaxf(v, 0.f);
          long idx = (gm0 + r) * (long)N + gn;
          if (Cf) Cf[idx] = v;
          if (Cb) Cb[idx] = f2bf(v);
        }
      }
    }
  }
}

// ---------------- MFMA flash attention, fixed-max softmax, async swizzled staging ----------------
__global__ __launch_bounds__(256) void attention_mfma(
    const u16* __restrict__ qkvb, const int* __restrict__ mask,
    const u16* __restrict__ vtg, u16* __restrict__ ctxb)
{
  __shared__ __align__(16) u16 Kb[64 * 64];
  __shared__ __align__(16) u16 Vt[64 * 64];
  __shared__ __align__(16) u16 Pl[4][16 * PST];
  __shared__ float negs[64];
  int tid = threadIdx.x;
  int wave = tid >> 6, lane = tid & 63;
  int l15 = lane & 15, quad = lane >> 4;
  int qt = blockIdx.x, bh = blockIdx.y;
  int b = bh / NH, h = bh - b * NH;
  long qtok = (long)b * SEQ + qt * 64;

  // Q fragments (A layout: m=lane&15, k=quad*8+j), 16B-aligned global loads
  bf16x8 aQ[2];
  {
    const u16* qp = qkvb + (qtok + wave * 16 + l15) * 2304 + h * 64 + quad * 8;
    aQ[0] = *(const bf16x8*)qp;
    aQ[1] = *(const bf16x8*)(qp + 32);
  }
  f32x4 oacc[4] = {};
  float lrow[4] = {0.f, 0.f, 0.f, 0.f};

  int r8 = lane >> 3;
  int g8 = ((lane & 7) ^ r8) * 8;
  int ck0 = wave * 2, ck1 = wave * 2 + 1;
  const u16* kg0 = qkvb + ((long)b * SEQ + ck0 * 8 + r8) * 2304 + 768 + h * 64 + g8;
  const u16* kg1 = qkvb + ((long)b * SEQ + ck1 * 8 + r8) * 2304 + 768 + h * 64 + g8;
  const u16* vg0 = vtg + ((long)bh * 64 + ck0 * 8 + r8) * SEQ + g8;
  const u16* vg1 = vtg + ((long)bh * 64 + ck1 * 8 + r8) * SEQ + g8;
  int sw = l15 & 7;
  int soff[2], aoffP[2];
  #pragma unroll
  for (int kc = 0; kc < 2; kc++) {
    soff[kc]  = l15 * 64 + 8 * ((kc * 4 + quad) ^ sw);   // + n*1024 / + d*1024
    aoffP[kc] = l15 * PST + kc * 32 + quad * 8;
  }
  u16* pw = &Pl[wave][0];

  for (int kt = 0; kt < 16; kt++) {
    __syncthreads();
    async16(kg0 + (long)kt * 64 * 2304, Kb + ck0 * 512);
    async16(kg1 + (long)kt * 64 * 2304, Kb + ck1 * 512);
    async16(vg0 + kt * 64, Vt + ck0 * 512);
    async16(vg1 + kt * 64, Vt + ck1 * 512);
    if (tid < 64) negs[tid] = (mask[(long)b * SEQ + kt * 64 + tid] == 0) ? -1e9f : 0.f;
    __syncthreads();

    // S strip = Q(16 rows) @ K^T(64 keys)
    f32x4 sa[4] = {};
    #pragma unroll
    for (int kc = 0; kc < 2; kc++)
      #pragma unroll
      for (int n = 0; n < 4; n++) {
        bf16x8 bk = *(const bf16x8*)&Kb[n * 1024 + soff[kc]];
        sa[n] = __builtin_amdgcn_mfma_f32_16x16x32_bf16(aQ[kc], bk, sa[n], 0, 0, 0);
      }
    float ng[4];
    #pragma unroll
    for (int n = 0; n < 4; n++) ng[n] = negs[n * 16 + l15];
    // fixed-max softmax: p = exp(s), s bounded (clamped for overflow safety)
    #pragma unroll
    for (int n = 0; n < 4; n++)
      #pragma unroll
      for (int r = 0; r < 4; r++) {
        float s = fminf(sa[n][r] * 0.125f + ng[n], 60.f);
        float p = __expf(s);
        lrow[r] += p;
        pw[(quad * 4 + r) * PST + n * 16 + l15] = f2bf(p);
      }
    #pragma unroll
    for (int kc = 0; kc < 2; kc++) {
      bf16x8 ap = *(const bf16x8*)&pw[aoffP[kc]];
      #pragma unroll
      for (int d = 0; d < 4; d++) {
        bf16x8 bv = *(const bf16x8*)&Vt[d * 1024 + soff[kc]];
        oacc[d] = __builtin_amdgcn_mfma_f32_16x16x32_bf16(ap, bv, oacc[d], 0, 0, 0);
      }
    }
  }

  // one final cross-lane reduce of the softmax denominators
  #pragma unroll
  for (int r = 0; r < 4; r++) {
    lrow[r] += __shfl_xor(lrow[r], 1, 64);
    lrow[r] += __shfl_xor(lrow[r], 2, 64);
    lrow[r] += __shfl_xor(lrow[r], 4, 64);
    lrow[r] += __shfl_xor(lrow[r], 8, 64);
  }
  float inv[4];
  #pragma unroll
  for (int r = 0; r < 4; r++) inv[r] = 1.f / lrow[r];
  #pragma unroll
  for (int d = 0; d < 4; d++)
    #pragma unroll
    for (int r = 0; r < 4; r++)
      pw[(quad * 4 + r) * PST + d * 16 + l15] = f2bf(oacc[d][r] * inv[r]);
  int orow = lane >> 2, ocol = (lane & 3) * 16;
  u16* og = ctxb + (qtok + wave * 16 + orow) * DM + h * 64 + ocol;
  *(uint4*)og       = *(const uint4*)&pw[orow * PST + ocol];
  *(uint4*)(og + 8) = *(const uint4*)&pw[orow * PST + ocol + 8];
}

// ---------------- fused residual + layernorm ----------------
__global__ __launch_bounds__(64) void ln_residual(
    const float* __restrict__ x, const float* __restrict__ y,
    const float* __restrict__ g, const float* __restrict__ b,
    float* __restrict__ xout, u16* __restrict__ xbout)
{
  long row = blockIdx.x;
  int t = threadIdx.x;
  const float* xr = x + row * DM;
  const float* yr = y + row * DM;
  float v[12];
  float sum = 0.f, sq = 0.f;
  #pragma unroll
  for (int j = 0; j < 3; j++) {
    int d = j * 256 + t * 4;
    float4 a = *(const float4*)(xr + d);
    float4 c = *(const float4*)(yr + d);
    float z0 = a.x + c.x, z1 = a.y + c.y, z2 = a.z + c.z, z3 = a.w + c.w;
    v[j*4+0] = z0; v[j*4+1] = z1; v[j*4+2] = z2; v[j*4+3] = z3;
    sum += z0 + z1 + z2 + z3;
    sq  += z0*z0 + z1*z1 + z2*z2 + z3*z3;
  }
  #pragma unroll
  for (int m = 1; m < 64; m <<= 1) {
    sum += __shfl_xor(sum, m, 64);
    sq  += __shfl_xor(sq,  m, 64);
  }
  float mu = sum * (1.f / 768.f);
  float var = sq * (1.f / 768.f) - mu * mu;
  float rstd = rsqrtf(var + 1e-5f);
  #pragma unroll
  for (int j = 0; j < 3; j++) {
    int d = j * 256 + t * 4;
    float4 gg = *(const float4*)(g + d);
    float4 bb = *(const float4*)(b + d);
    float z0 = (v[j*4+0] - mu) * rstd * gg.x + bb.x;
    float z1 = (v[j*4+1] - mu) * rstd * gg.y + bb.y;
    float z2 = (v[j*4+2] - mu) * rstd * gg.z + bb.z;
    float z3 = (v[j*4+3] - mu) * rstd * gg.w + bb.w;
    float4 fz; fz.x = z0; fz.y = z1; fz.z = z2; fz.w = z3;
    *(float4*)(xout + row * DM + d) = fz;
    uint2 pk;
    pk.x = f2bf(z0) | ((unsigned)f2bf(z1) << 16);
    pk.y = f2bf(z2) | ((unsigned)f2bf(z3) << 16);
    *(uint2*)(xbout + row * DM + d) = pk;
  }
}

// ---------------- classifier ----------------
__global__ __launch_bounds__(64) void classifier_kernel(
    const float* __restrict__ x, const float* __restrict__ w,
    const float* __restrict__ bias, float* __restrict__ out)
{
  int bc = blockIdx.x;
  int b = bc / NCLS, c = bc % NCLS;
  const float* xr = x + (long)b * SEQ * DM;
  float sum = 0.f;
  for (int d = threadIdx.x; d < DM; d += 64)
    sum += xr[d] * w[d * NCLS + c];
  #pragma unroll
  for (int m = 1; m < 64; m <<= 1) sum += __shfl_xor(sum, m, 64);
  if (threadIdx.x == 0) out[bc] = sum + bias[c];
}

extern "C" void kernel_launch(void* const* d_in, const int* in_sizes, int n_in,
                              void* d_out, int out_size, void* d_ws, size_t ws_size,
                              hipStream_t stream)
{
  const int*   ids  = (const int*)d_in[0];
  const int*   mask = (const int*)d_in[1];
  const float* emb  = (const float*)d_in[2];
  const float* wq   = (const float*)d_in[3];
  const float* bq   = (const float*)d_in[4];
  const float* wk   = (const float*)d_in[5];
  const float* bk   = (const float*)d_in[6];
  const float* wv   = (const float*)d_in[7];
  const float* bv   = (const float*)d_in[8];
  const float* wo   = (const float*)d_in[9];
  const float* bo   = (const float*)d_in[10];
  const float* ln1g = (const float*)d_in[11];
  const float* ln1b = (const float*)d_in[12];
  const float* w1   = (const float*)d_in[13];
  const float* b1   = (const float*)d_in[14];
  const float* w2   = (const float*)d_in[15];
  const float* b2   = (const float*)d_in[16];
  const float* ln2g = (const float*)d_in[17];
  const float* ln2b = (const float*)d_in[18];
  const float* clsw = (const float*)d_in[19];
  const float* clsb = (const float*)d_in[20];

  char* ws = (char*)d_ws;
  size_t off = 0;
  auto alloc = [&](size_t bytes) -> void* {
    void* p = ws + off;
    off += (bytes + 255) & ~(size_t)255;
    return p;
  };
  float* X     = (float*)alloc((size_t)NTOK * DM * 4);
  u16*   XB    = (u16*)  alloc((size_t)NTOK * DM * 2);
  u16*   QKVB16= (u16*)  alloc((size_t)NTOK * 2304 * 2);
  u16*   VT    = (u16*)  alloc((size_t)96 * 64 * SEQ * 2);
  u16*   CTXB  = (u16*)  alloc((size_t)NTOK * DM * 2);
  u16*   H1B   = (u16*)  alloc((size_t)NTOK * FD * 2);
  float* SCR   = (float*)alloc((size_t)NTOK * DM * 4);
  u16*   WQKVT = (u16*)  alloc((size_t)NLAYER * 2304 * 768 * 2);
  u16*   WOT   = (u16*)  alloc((size_t)NLAYER * 768 * 768 * 2);
  u16*   W1T   = (u16*)  alloc((size_t)NLAYER * 3072 * 768 * 2);
  u16*   W2T   = (u16*)  alloc((size_t)NLAYER * 768 * 3072 * 2);
  float* QKVB  = (float*)alloc((size_t)NLAYER * 2304 * 4);

  dim3 tb(32, 8);
  transpose_f32_bf16<<<dim3(24, 24, 6), tb, 0, stream>>>(wq, WQKVT, 768, 768, 768L*768, 2304L*768, 0);
  transpose_f32_bf16<<<dim3(24, 24, 6), tb, 0, stream>>>(wk, WQKVT, 768, 768, 768L*768, 2304L*768, 768L*768);
  transpose_f32_bf16<<<dim3(24, 24, 6), tb, 0, stream>>>(wv, WQKVT, 768, 768, 768L*768, 2304L*768, 1536L*768);
  transpose_f32_bf16<<<dim3(24, 24, 6), tb, 0, stream>>>(wo, WOT, 768, 768, 768L*768, 768L*768, 0);
  transpose_f32_bf16<<<dim3(96, 24, 6), tb, 0, stream>>>(w1, W1T, 768, 3072, 768L*3072, 3072L*768, 0);
  transpose_f32_bf16<<<dim3(24, 96, 6), tb, 0, stream>>>(w2, W2T, 3072, 768, 3072L*768, 768L*3072, 0);
  concat_bias<<<(NLAYER * 2304 + 255) / 256, 256, 0, stream>>>(bq, bk, bv, QKVB);
  embed_kernel<<<NTOK * DM / 1024, 256, 0, stream>>>(ids, emb, X, XB);

  for (int L = 0; L < NLAYER; L++) {
    gemm_bt<128><<<dim3(64, 18), 256, 0, stream>>>(
        XB, WQKVT + (size_t)L * 2304 * 768, QKVB + L * 2304,
        nullptr, QKVB16, VT, 2304, 768, 0);
    attention_mfma<<<dim3(16, 96), 256, 0, stream>>>(QKVB16, mask, VT, CTXB);
    gemm_bt<64><<<dim3(128, 6), 256, 0, stream>>>(
        CTXB, WOT + (size_t)L * 768 * 768, bo + L * 768,
        SCR, nullptr, nullptr, 768, 768, 0);
    ln_residual<<<NTOK, 64, 0, stream>>>(X, SCR, ln1g + L * 768, ln1b + L * 768, X, XB);
    gemm_bt<128><<<dim3(64, 24), 256, 0, stream>>>(
        XB, W1T + (size_t)L * 3072 * 768, b1 + L * 3072,
        nullptr, H1B, nullptr, 3072, 768, 1);
    gemm_bt<64><<<dim3(128, 6), 256, 0, stream>>>(
        H1B, W2T + (size_t)L * 768 * 3072, b2 + L * 768,
        SCR, nullptr, nullptr, 768, 3072, 0);
    ln_residual<<<NTOK, 64, 0, stream>>>(X, SCR, ln2g + L * 768, ln2b + L * 768, X, XB);
  }
  classifier_kernel<<<80, 64, 0, stream>>>(X, clsw, clsb, (float*)d_out);
}